// Round 1
// baseline (280.884 us; speedup 1.0000x reference)
//
#include <hip/hip_runtime.h>

#define BS 256
#define NB1 1024   // reduction blocks (4/CU) — partials = NB1*33 floats in d_ws
#define NB3 2048   // add blocks

// Pass 1: s[j] = sum_i w_i * x[i][j]  (j=0..31), wsum = sum_i w_i.
// Per-block deterministic partials written to colpart[b*32+j], wpart[b].
// Thread t handles float4 chunk c (row = c>>3, colgroup = c&7 == t&7 since
// grid stride is a multiple of 8).
__global__ void __launch_bounds__(BS) reduce_kernel(
    const float* __restrict__ x, const float* __restrict__ w,
    float* __restrict__ colpart, float* __restrict__ wpart, long long total4) {
  const int tid = threadIdx.x;
  const long long stride = (long long)gridDim.x * BS;
  const float4* x4 = (const float4*)x;
  float4 acc = make_float4(0.f, 0.f, 0.f, 0.f);
  float wacc = 0.f;
  const bool is_w = ((tid & 7) == 0);  // one of the 8 threads per row counts w
  for (long long c = (long long)blockIdx.x * BS + tid; c < total4; c += stride) {
    const int row = (int)(c >> 3);
    const float wi = w[row];
    const float4 v = x4[c];
    acc.x = fmaf(wi, v.x, acc.x);
    acc.y = fmaf(wi, v.y, acc.y);
    acc.z = fmaf(wi, v.z, acc.z);
    acc.w = fmaf(wi, v.w, acc.w);
    if (is_w) wacc += wi;
  }
  __shared__ float4 sacc[BS];
  __shared__ float  sw[BS];
  sacc[tid] = acc;
  sw[tid] = wacc;
  __syncthreads();
  // tree-reduce; stop at s=8 so columns (tid&7) stay separated
  for (int s = BS / 2; s >= 8; s >>= 1) {
    if (tid < s) {
      float4 o = sacc[tid + s];
      sacc[tid].x += o.x; sacc[tid].y += o.y;
      sacc[tid].z += o.z; sacc[tid].w += o.w;
      sw[tid] += sw[tid + s];
    }
    __syncthreads();
  }
  if (tid < 8) {
    ((float4*)(colpart + (long long)blockIdx.x * 32))[tid] = sacc[tid];
  }
  if (tid == 0) {
    float wsum = sw[0] + sw[1] + sw[2] + sw[3] + sw[4] + sw[5] + sw[6] + sw[7];
    wpart[blockIdx.x] = wsum;
  }
}

// Stage 2 (single block): finish reduction, compute r = W_out @ relu(W_in @ avg)
__global__ void __launch_bounds__(BS) middle_kernel(
    const float* __restrict__ colpart, const float* __restrict__ wpart,
    const float* __restrict__ W_in, const float* __restrict__ W_out,
    float* __restrict__ r_out, int nb) {
  __shared__ float red[BS];
  __shared__ float wred[BS];
  __shared__ float avg[32];
  __shared__ float h[128];
  const int tid = threadIdx.x;
  {
    const int col = tid & 31, grp = tid >> 5;  // 8 groups over blocks
    float s = 0.f;
    for (int b = grp; b < nb; b += 8) s += colpart[b * 32 + col];
    red[tid] = s;
  }
  {
    float s = 0.f;
    for (int b = tid; b < nb; b += BS) s += wpart[b];
    wred[tid] = s;
  }
  __syncthreads();
  for (int s = BS / 2; s >= 1; s >>= 1) {
    if (tid < s) wred[tid] += wred[tid + s];
    __syncthreads();
  }
  if (tid < 32) {
    float s = 0.f;
    for (int g = 0; g < 8; ++g) s += red[tid + 32 * g];
    avg[tid] = s / wred[0];
  }
  __syncthreads();
  if (tid < 128) {
    float a = 0.f;
    for (int k = 0; k < 32; ++k) a = fmaf(W_in[tid * 32 + k], avg[k], a);
    h[tid] = fmaxf(a, 0.f);
  }
  __syncthreads();
  if (tid < 32) {
    float r = 0.f;
    for (int k = 0; k < 128; ++k) r = fmaf(W_out[tid * 128 + k], h[k], r);
    r_out[tid] = r;
  }
}

// Pass 2: out[i][j] = x[i][j] + r[j], float4-vectorized.
__global__ void __launch_bounds__(BS) add_kernel(
    const float* __restrict__ x, const float* __restrict__ r,
    float* __restrict__ out, long long total4) {
  const int tid = threadIdx.x;
  __shared__ float4 rs[8];
  if (tid < 8) rs[tid] = ((const float4*)r)[tid];
  __syncthreads();
  const float4 rr = rs[tid & 7];  // loop-invariant: stride % 8 == 0
  const long long stride = (long long)gridDim.x * BS;
  const float4* x4 = (const float4*)x;
  float4* o4 = (float4*)out;
  for (long long c = (long long)blockIdx.x * BS + tid; c < total4; c += stride) {
    float4 v = x4[c];
    v.x += rr.x; v.y += rr.y; v.z += rr.z; v.w += rr.w;
    o4[c] = v;
  }
}

extern "C" void kernel_launch(void* const* d_in, const int* in_sizes, int n_in,
                              void* d_out, int out_size, void* d_ws, size_t ws_size,
                              hipStream_t stream) {
  const float* x     = (const float*)d_in[0];
  const float* w     = (const float*)d_in[1];
  const float* W_in  = (const float*)d_in[2];
  const float* W_out = (const float*)d_in[3];
  float* out = (float*)d_out;

  const long long N = (long long)in_sizes[0] / 32;
  const long long total4 = N * 8;  // float4 chunks (32 floats/row = 8 float4)

  // workspace layout: colpart[nb*32] | wpart[nb] | r[32]
  int nb = NB1;
  while (nb > 64 && (size_t)(nb * 33 + 32) * 4 > ws_size) nb >>= 1;
  float* colpart = (float*)d_ws;
  float* wpart   = colpart + (size_t)nb * 32;
  float* r       = wpart + nb;  // nb*33*4 bytes offset, 16B-aligned for nb%4==0

  reduce_kernel<<<nb, BS, 0, stream>>>(x, w, colpart, wpart, total4);
  middle_kernel<<<1, BS, 0, stream>>>(colpart, wpart, W_in, W_out, r, nb);
  add_kernel<<<NB3, BS, 0, stream>>>(x, r, out, total4);
}

// Round 3
// 265.491 us; speedup vs baseline: 1.0580x; 1.0580x over previous
//
#include <hip/hip_runtime.h>

#define BS 256
#define NB1 2048   // reduction blocks (8/CU) — partials = NB1*33 floats in d_ws
#define NB3 2048   // add blocks

typedef float vfloat4 __attribute__((ext_vector_type(4)));

// Pass 1: colpart[b*32+j] = block-partial of sum_i w_i * x[i][j], wpart[b] =
// 8 * block-partial of sum_i w_i (each row's w counted once per float4 chunk,
// i.e. 8x; corrected by *0.125 in middle_kernel — exact binary scaling).
// Chunk c has column group c%8 == tid%8 (all strides are multiples of 8).
__global__ void __launch_bounds__(BS) reduce_kernel(
    const float* __restrict__ x, const float* __restrict__ w,
    float* __restrict__ colpart, float* __restrict__ wpart, long long total4) {
  const int tid = threadIdx.x;
  const long long stride2 = (long long)gridDim.x * (2 * BS);
  const vfloat4* x4 = (const vfloat4*)x;
  vfloat4 a0 = (vfloat4)(0.f);
  vfloat4 a1 = (vfloat4)(0.f);
  float w0 = 0.f, w1 = 0.f;
  long long c = (long long)blockIdx.x * (2 * BS) + tid;
  for (; c + BS < total4; c += stride2) {
    const float wi0 = w[(int)(c >> 3)];
    const float wi1 = w[(int)((c + BS) >> 3)];
    const vfloat4 v0 = x4[c];
    const vfloat4 v1 = x4[c + BS];
    a0 += wi0 * v0;
    a1 += wi1 * v1;
    w0 += wi0; w1 += wi1;
  }
  if (c < total4) {  // tail: lone chunk without an in-range partner
    const float wi = w[(int)(c >> 3)];
    a0 += wi * x4[c];
    w0 += wi;
  }
  a0 += a1;
  w0 += w1;
  __shared__ vfloat4 sacc[BS];
  __shared__ float   sw[BS];
  sacc[tid] = a0;
  sw[tid] = w0;
  __syncthreads();
  // tree-reduce; stop at s=8 so column groups (tid&7) stay separated
  for (int s = BS / 2; s >= 8; s >>= 1) {
    if (tid < s) {
      sacc[tid] += sacc[tid + s];
      sw[tid] += sw[tid + s];
    }
    __syncthreads();
  }
  if (tid < 8) {
    ((vfloat4*)(colpart + (long long)blockIdx.x * 32))[tid] = sacc[tid];
  }
  if (tid == 0) {
    wpart[blockIdx.x] = sw[0] + sw[1] + sw[2] + sw[3] +
                        sw[4] + sw[5] + sw[6] + sw[7];
  }
}

// Stage 2 (single block): finish reduction, r = W_out @ relu(W_in @ avg)
__global__ void __launch_bounds__(BS) middle_kernel(
    const float* __restrict__ colpart, const float* __restrict__ wpart,
    const float* __restrict__ W_in, const float* __restrict__ W_out,
    float* __restrict__ r_out, int nb) {
  const int tid = threadIdx.x;
  __shared__ vfloat4 sacc[BS];
  __shared__ float   swr[BS];
  __shared__ float   avg[32];
  __shared__ float   h[128];
  // column partials: colpart as vfloat4; chunk's column-quad = cb&7 == tid&7
  {
    const vfloat4* cp4 = (const vfloat4*)colpart;
    const int nchunk = nb * 8;
    vfloat4 acc = (vfloat4)(0.f);
    for (int cb = tid; cb < nchunk; cb += BS) acc += cp4[cb];
    sacc[tid] = acc;
  }
  {
    const vfloat4* wp4 = (const vfloat4*)wpart;
    const int nchunk = nb / 4;
    float s = 0.f;
    for (int cb = tid; cb < nchunk; cb += BS) {
      vfloat4 v = wp4[cb];
      s += v.x + v.y + v.z + v.w;
    }
    swr[tid] = s;
  }
  __syncthreads();
  for (int s = BS / 2; s >= 8; s >>= 1) {
    if (tid < s) {
      sacc[tid] += sacc[tid + s];
      swr[tid] += swr[tid + s];
    }
    __syncthreads();
  }
  if (tid == 0) {
    // wpart counted each w 8x (once per chunk) -> *0.125 (exact)
    float wsum = (swr[0] + swr[1] + swr[2] + swr[3] +
                  swr[4] + swr[5] + swr[6] + swr[7]) * 0.125f;
    swr[0] = wsum;
  }
  __syncthreads();
  if (tid < 32) {
    // column j lives in sacc[j>>2] component j&3
    const float* sflat = (const float*)sacc;
    avg[tid] = sflat[tid] / swr[0];
  }
  __syncthreads();
  if (tid < 128) {
    float a = 0.f;
    for (int k = 0; k < 32; ++k) a = fmaf(W_in[tid * 32 + k], avg[k], a);
    h[tid] = fmaxf(a, 0.f);
  }
  __syncthreads();
  if (tid < 32) {
    float r = 0.f;
    for (int k = 0; k < 128; ++k) r = fmaf(W_out[tid * 128 + k], h[k], r);
    r_out[tid] = r;
  }
}

// Pass 2: out[i][j] = x[i][j] + r[j]; x read (L3-warm), out via NT stores.
__global__ void __launch_bounds__(BS) add_kernel(
    const float* __restrict__ x, const float* __restrict__ r,
    float* __restrict__ out, long long total4) {
  const int tid = threadIdx.x;
  const vfloat4 rr = ((const vfloat4*)r)[tid & 7];  // chunk col-quad == tid&7
  const long long stride2 = (long long)gridDim.x * (2 * BS);
  const vfloat4* x4 = (const vfloat4*)x;
  vfloat4* o4 = (vfloat4*)out;
  long long c = (long long)blockIdx.x * (2 * BS) + tid;
  for (; c + BS < total4; c += stride2) {
    vfloat4 v0 = x4[c] + rr;
    vfloat4 v1 = x4[c + BS] + rr;
    __builtin_nontemporal_store(v0, &o4[c]);
    __builtin_nontemporal_store(v1, &o4[c + BS]);
  }
  if (c < total4) {
    vfloat4 v = x4[c] + rr;
    __builtin_nontemporal_store(v, &o4[c]);
  }
}

extern "C" void kernel_launch(void* const* d_in, const int* in_sizes, int n_in,
                              void* d_out, int out_size, void* d_ws, size_t ws_size,
                              hipStream_t stream) {
  const float* x     = (const float*)d_in[0];
  const float* w     = (const float*)d_in[1];
  const float* W_in  = (const float*)d_in[2];
  const float* W_out = (const float*)d_in[3];
  float* out = (float*)d_out;

  const long long N = (long long)in_sizes[0] / 32;
  const long long total4 = N * 8;  // float4 chunks (32 floats/row = 8 float4)

  // workspace layout: colpart[nb*32] | wpart[nb] | r[32]
  int nb = NB1;
  while (nb > 64 && (size_t)(nb * 33 + 32) * 4 > ws_size) nb >>= 1;
  float* colpart = (float*)d_ws;
  float* wpart   = colpart + (size_t)nb * 32;
  float* r       = wpart + nb;  // 16B-aligned: nb*33*4 % 16 == 0 for nb%4==0

  reduce_kernel<<<nb, BS, 0, stream>>>(x, w, colpart, wpart, total4);
  middle_kernel<<<1, BS, 0, stream>>>(colpart, wpart, W_in, W_out, r, nb);
  add_kernel<<<NB3, BS, 0, stream>>>(x, r, out, total4);
}